// Round 19
// baseline (56.527 us; speedup 1.0000x reference)
//
#include <hip/hip_runtime.h>
#include <math.h>

#define M_  2
#define B_  256
#define L_  1024
#define K_  4
#define S_  20
#define NR_ 100
#define NTERM 7   // Taylor terms T_1..T_7 ; ||mu*Q||inf <= 0.13 -> rem ~2e-11

typedef float f32x4_t __attribute__((ext_vector_type(4)));

__device__ __forceinline__ float softplusf(float x) {
    return x > 20.0f ? x : log1pf(expf(x));
}

// ---------------------------------------------------------------------------
// Kernel 1: per (m,k), compute normalized Q, store T_n = Q^n/n!, n=1..NTERM.
// 8 blocks (the serial chain lives here only). [R16 lesson: do NOT fuse the
// 100-r loop into this 8-block kernel -- latency-bound on 8 CUs, ~+44us.]
// ---------------------------------------------------------------------------
__global__ __launch_bounds__(512)
void qpow_kernel(const float* __restrict__ exch,   // (M,K,S,S)
                 const float* __restrict__ equil,  // (M,K,S)
                 float*       __restrict__ Qpow)   // (M,K,NTERM,400)
{
    __shared__ float sQ[400];
    __shared__ float sT[2][400];
    __shared__ float sRow[20];

    const int blk = blockIdx.x;          // mm*K_ + kk
    const int kk = blk % K_;
    const int mm = blk / K_;
    const int tid = threadIdx.x;
    const bool act = tid < 400;
    const int i = tid / 20;
    const int j = tid - i * 20;

    float p[20];
    float Q0 = 0.0f, rowsum = 0.0f;

    if (act) {
        const float* eq = equil + (mm * K_ + kk) * S_;
        float mx = eq[0];
        #pragma unroll
        for (int z = 1; z < 20; ++z) mx = fmaxf(mx, eq[z]);
        float s = 0.0f;
        #pragma unroll
        for (int z = 0; z < 20; ++z) { p[z] = expf(eq[z] - mx); s += p[z]; }
        const float inv = 1.0f / s;
        #pragma unroll
        for (int z = 0; z < 20; ++z) p[z] *= inv;

        const float* Kx = exch + (mm * K_ + kk) * S_ * S_;
        float R = (i == j) ? 0.0f : softplusf(0.5f * (Kx[i * 20 + j] + Kx[j * 20 + i]));
        Q0 = R * p[j];
        sQ[tid] = Q0;
    }
    __syncthreads();

    if (act) {
        rowsum = 0.0f;
        #pragma unroll
        for (int z = 0; z < 20; ++z) rowsum += sQ[i * 20 + z];
        if (j == 0) sRow[i] = rowsum;
    }
    __syncthreads();

    float* Tout = Qpow + (size_t)blk * (NTERM * 400);
    if (act) {
        float mue = 0.0f;
        #pragma unroll
        for (int z = 0; z < 20; ++z) mue += p[z] * sRow[z];
        float q = (Q0 - ((i == j) ? rowsum : 0.0f)) / fmaxf(mue, 1e-16f);
        sQ[tid] = q;
        sT[0][tid] = q;
        Tout[tid] = q;       // T_1 = Q
    }
    __syncthreads();

    int cur = 0;
    for (int n = 2; n <= NTERM; ++n) {
        if (act) {
            float acc = 0.0f;
            #pragma unroll
            for (int z = 0; z < 20; ++z) acc += sT[cur][i * 20 + z] * sQ[z * 20 + j];
            acc /= (float)n;
            sT[cur ^ 1][tid] = acc;
            Tout[(n - 1) * 400 + tid] = acc;   // T_n = Q^n / n!
        }
        __syncthreads();
        cur ^= 1;
    }
}

// ---------------------------------------------------------------------------
// Kernel 2: P[m,r,k] = I + sum_n mu^n T_n  (linear combo, no matmuls).
// 800 blocks -- wide and parallel (beats the fused producer by ~44us).
// ---------------------------------------------------------------------------
__global__ __launch_bounds__(512)
void pbuild_kernel(const float* __restrict__ Qpow,  // (M,K,NTERM,400)
                   const float* __restrict__ tauk,  // (M,NR)
                   const float* __restrict__ pmrk,  // (M,K)
                   float*       __restrict__ Pws)   // (M,NR,K,400)
{
    const int blk = blockIdx.x;          // mm*NR*K + rr*K + kk
    const int kk = blk % K_;
    const int rr = (blk / K_) % NR_;
    const int mm = blk / (K_ * NR_);
    const int tid = threadIdx.x;
    if (tid >= 400) return;

    const float mu = softplusf(tauk[mm * NR_ + rr]) * softplusf(pmrk[mm * K_ + kk]);
    const float* T = Qpow + ((size_t)(mm * K_ + kk) * NTERM) * 400 + tid;

    float acc = (tid % 21 == 0) ? 1.0f : 0.0f;   // identity
    float mp = mu;
    #pragma unroll
    for (int n = 0; n < NTERM; ++n) { acc = fmaf(mp, T[n * 400], acc); mp *= mu; }
    Pws[(size_t)blk * 400 + tid] = acc;
}

// ---------------------------------------------------------------------------
// Kernel 3: champion einsum + 2-phase double-buffered DMA pipeline.
// Block owns 512 rows = 2 phases x 256 rows. stage0+P -> sync ->
// issue stage1 DMA -> compute0 (hides stage1) -> vmcnt(0) [only DMAs
// outstanding, ~free] -> s_barrier -> stores0 || compute1 -> stores1.
// Stores are never drained mid-kernel. LDS 46.4 KB; 1024 blocks x 320 thr.
// ---------------------------------------------------------------------------
#define CHUNKR 256
#define TPB3   320

__device__ __forceinline__ void fma4(float4& a, float s, const float4& p) {
    a.x = fmaf(s, p.x, a.x);
    a.y = fmaf(s, p.y, a.y);
    a.z = fmaf(s, p.z, a.z);
    a.w = fmaf(s, p.w, a.w);
}

__device__ __forceinline__ void nt_store4(float* dst, const float4& v) {
    f32x4_t w;
    w.x = v.x; w.y = v.y; w.z = v.z; w.w = v.w;
    __builtin_nontemporal_store(w, (f32x4_t*)dst);
}

__device__ __forceinline__ void dma16(const void* gsrc, void* lds_base) {
    __builtin_amdgcn_global_load_lds(
        (const __attribute__((address_space(1))) void*)gsrc,
        (__attribute__((address_space(3))) void*)lds_base,
        16, 0, 0);
}

// stage one 256-row chunk (20 KB) via DMA: 20 x 1KB wave-chunks, 5 waves x 4
__device__ __forceinline__ void stage_chunk(const char* gin, char* lin,
                                            int wave, int lane) {
    #pragma unroll
    for (int q = 0; q < 4; ++q) {
        const int off = (q * 5 + wave) * 1024;
        dma16(gin + off + lane * 16, lin + off);
    }
}

// compute+accumulate 256 rows from inbuf, write acc to registers, NT-store
__device__ __forceinline__ void compute_chunk(const float* inbuf, const float* Pk,
                                              float* ob, int rg) {
    float4 acc[16];
    #pragma unroll
    for (int rr = 0; rr < 16; ++rr) acc[rr] = make_float4(0.f, 0.f, 0.f, 0.f);

    #pragma unroll
    for (int z4 = 0; z4 < 5; ++z4) {
        const float4 p0 = *(const float4*)(Pk + (z4 * 4 + 0) * 20);
        const float4 p1 = *(const float4*)(Pk + (z4 * 4 + 1) * 20);
        const float4 p2 = *(const float4*)(Pk + (z4 * 4 + 2) * 20);
        const float4 p3 = *(const float4*)(Pk + (z4 * 4 + 3) * 20);
        #pragma unroll
        for (int rr = 0; rr < 16; ++rr) {
            const int l = rg + rr * 16;
            const float4 av = *(const float4*)(inbuf + l * 20 + z4 * 4);
            fma4(acc[rr], av.x, p0);
            fma4(acc[rr], av.y, p1);
            fma4(acc[rr], av.z, p2);
            fma4(acc[rr], av.w, p3);
        }
    }

    #pragma unroll
    for (int rr = 0; rr < 16; ++rr) {
        const int l = rg + rr * 16;
        nt_store4(ob + (size_t)l * 80, acc[rr]);
    }
}

__global__ __launch_bounds__(TPB3)
void einsum_kernel(const float* __restrict__ inp,  // (M,B,L,S)
                   const float* __restrict__ Pws,  // (M,NR,K,400)
                   const int*   __restrict__ ridx, // (M,B)
                   float*       __restrict__ out)  // (M,B,L,K*S)
{
    __shared__ float Pl[K_ * 400];              //  6400 B  [k][z][s]
    __shared__ float inL0[CHUNKR * 20];         // 20480 B
    __shared__ float inL1[CHUNKR * 20];         // 20480 B

    // XCD-aware bijective swizzle: 1024 = 8 * 128
    const int bx0  = blockIdx.x;
    const int bx   = (bx0 & 7) * 128 + (bx0 >> 3);
    const int half = bx & 1;                    // L_/512 = 2
    const int mb   = bx >> 1;                   // 0..511
    const int mm   = mb >> 8;
    const int tid  = threadIdx.x;
    const int wave = tid >> 6;
    const int lane = tid & 63;
    const int t    = tid % 20;
    const int rg   = tid / 20;                  // 0..15
    const int k    = t / 5;
    const int s0   = (t % 5) * 4;

    const int r = ridx[mb];                     // block-uniform

    const size_t row0 = (size_t)mb * L_ + (size_t)half * 512;
    const char* gin = (const char*)(inp + row0 * 20);

    // ---- stage chunk 0 + P via DMA ----
    stage_chunk(gin, (char*)inL0, wave, lane);
    {
        const char* gp = (const char*)(Pws + ((size_t)(mm * NR_ + r) * K_) * 400);
        char* lp = (char*)Pl;
        {
            const int off = wave * 1024;            // chunks 0..319
            dma16(gp + off + lane * 16, lp + off);
        }
        if (tid < 80) {                             // chunks 320..399
            const int off = 5120 + wave * 1024;
            dma16(gp + off + lane * 16, lp + off);
        }
    }
    __syncthreads();                // drains vmcnt(0): chunk0 + P ready

    // ---- issue chunk 1 DMA (flies under compute0) ----
    stage_chunk(gin + CHUNKR * 80, (char*)inL1, wave, lane);

    const float* Pk = Pl + k * 400 + s0;
    float* ob = out + row0 * 80 + k * 20 + s0;

    // ---- phase 0: compute + NT stores (stores issued after the barrier
    //      below would be ideal, but they are independent of it; keeping
    //      them here lets them overlap the ~free vmcnt wait) ----
    compute_chunk(inL0, Pk, ob, rg);

    // wait DMA1 only: stores from phase 0 were issued after the DMAs, so
    // vmcnt(16) leaves the 16 NT stores outstanding and waits the 4 DMAs.
    asm volatile("s_waitcnt vmcnt(16)" ::: "memory");
    __builtin_amdgcn_s_barrier();
    __builtin_amdgcn_sched_barrier(0);

    // ---- phase 1 ----
    compute_chunk(inL1, Pk, ob + (size_t)CHUNKR * 80, rg);
}

// ---------------------------------------------------------------------------
extern "C" void kernel_launch(void* const* d_in, const int* in_sizes, int n_in,
                              void* d_out, int out_size, void* d_ws, size_t ws_size,
                              hipStream_t stream) {
    const float* inp   = (const float*)d_in[0];  // (M,B,L,S)
    const float* tauk  = (const float*)d_in[1];  // (M,NR)
    const float* exch  = (const float*)d_in[2];  // (M,K,S,S)
    const float* equil = (const float*)d_in[3];  // (M,K,S)
    const float* pmrk  = (const float*)d_in[4];  // (M,K)
    const int*   ridx  = (const int*)d_in[5];    // (M,B)
    float* outp = (float*)d_out;

    float* Qpow = (float*)d_ws;                          // 89.6 KB
    float* Pws  = Qpow + (size_t)M_ * K_ * NTERM * 400;  // 1.28 MB

    qpow_kernel<<<M_ * K_, 512, 0, stream>>>(exch, equil, Qpow);
    pbuild_kernel<<<M_ * NR_ * K_, 512, 0, stream>>>(Qpow, tauk, pmrk, Pws);
    einsum_kernel<<<M_ * B_ * (L_ / 512), TPB3, 0, stream>>>(inp, Pws, ridx, outp);
}

// Round 20
// 50.768 us; speedup vs baseline: 1.1134x; 1.1134x over previous
//
#include <hip/hip_runtime.h>
#include <math.h>

#define M_  2
#define B_  256
#define L_  1024
#define K_  4
#define S_  20
#define NR_ 100
#define NTERM 7   // Taylor terms T_1..T_7 ; ||mu*Q||inf <= 0.13 -> rem ~2e-11

typedef float f32x4_t __attribute__((ext_vector_type(4)));
typedef _Float16 f16;
typedef f16 f16x8 __attribute__((ext_vector_type(8)));
typedef f16 f16x4 __attribute__((ext_vector_type(4)));

__device__ __forceinline__ float softplusf(float x) {
    return x > 20.0f ? x : log1pf(expf(x));
}

// ---------------------------------------------------------------------------
// Kernel 1: per (m,k), compute normalized Q, store T_n = Q^n/n!, n=1..NTERM.
// 8 blocks (serial chain lives here only; R16: never fuse the r-loop here).
// ---------------------------------------------------------------------------
__global__ __launch_bounds__(512)
void qpow_kernel(const float* __restrict__ exch,   // (M,K,S,S)
                 const float* __restrict__ equil,  // (M,K,S)
                 float*       __restrict__ Qpow)   // (M,K,NTERM,400)
{
    __shared__ float sQ[400];
    __shared__ float sT[2][400];
    __shared__ float sRow[20];

    const int blk = blockIdx.x;          // mm*K_ + kk
    const int kk = blk % K_;
    const int mm = blk / K_;
    const int tid = threadIdx.x;
    const bool act = tid < 400;
    const int i = tid / 20;
    const int j = tid - i * 20;

    float p[20];
    float Q0 = 0.0f, rowsum = 0.0f;

    if (act) {
        const float* eq = equil + (mm * K_ + kk) * S_;
        float mx = eq[0];
        #pragma unroll
        for (int z = 1; z < 20; ++z) mx = fmaxf(mx, eq[z]);
        float s = 0.0f;
        #pragma unroll
        for (int z = 0; z < 20; ++z) { p[z] = expf(eq[z] - mx); s += p[z]; }
        const float inv = 1.0f / s;
        #pragma unroll
        for (int z = 0; z < 20; ++z) p[z] *= inv;

        const float* Kx = exch + (mm * K_ + kk) * S_ * S_;
        float R = (i == j) ? 0.0f : softplusf(0.5f * (Kx[i * 20 + j] + Kx[j * 20 + i]));
        Q0 = R * p[j];
        sQ[tid] = Q0;
    }
    __syncthreads();

    if (act) {
        rowsum = 0.0f;
        #pragma unroll
        for (int z = 0; z < 20; ++z) rowsum += sQ[i * 20 + z];
        if (j == 0) sRow[i] = rowsum;
    }
    __syncthreads();

    float* Tout = Qpow + (size_t)blk * (NTERM * 400);
    if (act) {
        float mue = 0.0f;
        #pragma unroll
        for (int z = 0; z < 20; ++z) mue += p[z] * sRow[z];
        float q = (Q0 - ((i == j) ? rowsum : 0.0f)) / fmaxf(mue, 1e-16f);
        sQ[tid] = q;
        sT[0][tid] = q;
        Tout[tid] = q;       // T_1 = Q
    }
    __syncthreads();

    int cur = 0;
    for (int n = 2; n <= NTERM; ++n) {
        if (act) {
            float acc = 0.0f;
            #pragma unroll
            for (int z = 0; z < 20; ++z) acc += sT[cur][i * 20 + z] * sQ[z * 20 + j];
            acc /= (float)n;
            sT[cur ^ 1][tid] = acc;
            Tout[(n - 1) * 400 + tid] = acc;   // T_n = Q^n / n!
        }
        __syncthreads();
        cur ^= 1;
    }
}

// ---------------------------------------------------------------------------
// Kernel 2: P[m,r,k] = I + sum_n mu^n T_n  (linear combo, no matmuls).
// 800 blocks -- wide and parallel (the fused 8-block producer costs ~52us).
// ---------------------------------------------------------------------------
__global__ __launch_bounds__(512)
void pbuild_kernel(const float* __restrict__ Qpow,  // (M,K,NTERM,400)
                   const float* __restrict__ tauk,  // (M,NR)
                   const float* __restrict__ pmrk,  // (M,K)
                   float*       __restrict__ Pws)   // (M,NR,K,400)
{
    const int blk = blockIdx.x;          // mm*NR*K + rr*K + kk
    const int kk = blk % K_;
    const int rr = (blk / K_) % NR_;
    const int mm = blk / (K_ * NR_);
    const int tid = threadIdx.x;
    if (tid >= 400) return;

    const float mu = softplusf(tauk[mm * NR_ + rr]) * softplusf(pmrk[mm * K_ + kk]);
    const float* T = Qpow + ((size_t)(mm * K_ + kk) * NTERM) * 400 + tid;

    float acc = (tid % 21 == 0) ? 1.0f : 0.0f;   // identity
    float mp = mu;
    #pragma unroll
    for (int n = 0; n < NTERM; ++n) { acc = fmaf(mp, T[n * 400], acc); mp *= mu; }
    Pws[(size_t)blk * 400 + tid] = acc;
}

// ---------------------------------------------------------------------------
// Kernel 3 (MFMA, swapped operands, through-L2 stores) -- R13's einsum
// verbatim. out(256x80) = A(256x20)P(20x80) as D = P^T A^T per 16x16 tile
// (one mfma_f32_16x16x32_f16, K padded to 32, C-in = 0). Lane stores one
// f32x4 (4 contiguous cols of an output row) THROUGH L2 (write-combine
// assembles the 64B/row segments; NT here cost +19us, R12 vs R13).
// Reconciled R13 einsum cost ~= 40-42us (94.1 total - ~52 pmat).
// 2048 blocks x 256 threads; one barrier; LDS 26.9 KB.
// ---------------------------------------------------------------------------
#define TPB3 256

__global__ __launch_bounds__(TPB3)
void einsum_kernel(const float* __restrict__ inp,  // (M,B,L,S)
                   const float* __restrict__ Pws,  // (M,NR,K,400)
                   const int*   __restrict__ ridx, // (M,B)
                   float*       __restrict__ out)  // (M,B,L,K*S)
{
    __shared__ __align__(16) f16 A_lds[256 * 40];   // 20480 B, [row l][z] pad40
    __shared__ __align__(16) f16 P_ldsT[80 * 40];   //  6400 B, [n][z]    pad40

    const int bx      = blockIdx.x;
    const int quarter = bx & 3;            // L_/256 = 4
    const int mb      = bx >> 2;           // 0..511
    const int mm      = mb >> 8;
    const int tid     = threadIdx.x;

    const int r = ridx[mb];                // block-uniform
    const size_t row0 = (size_t)mb * L_ + (size_t)quarter * 256;

    // ---- stage A: 256 rows x 20 f32 -> f16, coalesced float4 loads ----
    {
        const float4* Isrc = (const float4*)(inp + row0 * 20);
        #pragma unroll
        for (int q = 0; q < 5; ++q) {
            const int e  = tid + q * TPB3;     // 0..1279
            const int rr = e / 5;
            const int cc = e - rr * 5;
            const float4 v = Isrc[e];
            f16x4 h = { (f16)v.x, (f16)v.y, (f16)v.z, (f16)v.w };
            *(f16x4*)&A_lds[rr * 40 + cc * 4] = h;
        }
        const f16x4 z4 = {(f16)0, (f16)0, (f16)0, (f16)0};
        *(f16x4*)&A_lds[tid * 40 + 20] = z4;   // zero K-pad 20..31
        *(f16x4*)&A_lds[tid * 40 + 24] = z4;
        *(f16x4*)&A_lds[tid * 40 + 28] = z4;
    }

    // ---- stage P transposed: P_ldsT[n=kk*20+s][z] = P[z][s] of matrix kk ----
    {
        const float* Psrc = Pws + ((size_t)(mm * NR_ + r) * K_) * 400;
        for (int idx = tid; idx < 1600; idx += TPB3) {
            const int n  = idx / 20;
            const int z  = idx - n * 20;
            const int kk = n / 20;
            const int s  = n - kk * 20;
            P_ldsT[n * 40 + z] = (f16)Psrc[kk * 400 + z * 20 + s];
        }
        if (tid < 80) {
            const f16x4 z4 = {(f16)0, (f16)0, (f16)0, (f16)0};
            *(f16x4*)&P_ldsT[tid * 40 + 20] = z4;
            *(f16x4*)&P_ldsT[tid * 40 + 24] = z4;
            *(f16x4*)&P_ldsT[tid * 40 + 28] = z4;
        }
    }
    __syncthreads();                       // the ONLY barrier

    const int wave = tid >> 6;
    const int lane = tid & 63;
    const int lrow = lane & 15;            // frag row/col within tile
    const int lk   = (lane >> 4) * 8;      // K-group offset
    const int crow = (lane >> 4) * 4;      // D row base (= output col base)

    // A-operand fragments: P^T rows n = nt*16+lrow, k-contiguous
    f16x8 Pf[5];
    #pragma unroll
    for (int nt = 0; nt < 5; ++nt)
        Pf[nt] = *(const f16x8*)&P_ldsT[(nt * 16 + lrow) * 40 + lk];

    const f32x4_t cz = {0.f, 0.f, 0.f, 0.f};

    #pragma unroll
    for (int tm = 0; tm < 4; ++tm) {
        const int tile = wave * 4 + tm;    // 0..15 M-tiles
        // B-operand fragment: A row l = tile*16+lrow, k-contiguous
        const f16x8 Af = *(const f16x8*)&A_lds[(tile * 16 + lrow) * 40 + lk];
        float* orow = out + (row0 + tile * 16 + lrow) * 80;
        #pragma unroll
        for (int nt = 0; nt < 5; ++nt) {
            f32x4_t c = __builtin_amdgcn_mfma_f32_16x16x32_f16(Pf[nt], Af, cz, 0, 0, 0);
            *(f32x4_t*)(orow + nt * 16 + crow) = c;   // through L2 (write-combine)
        }
    }
}

// ---------------------------------------------------------------------------
extern "C" void kernel_launch(void* const* d_in, const int* in_sizes, int n_in,
                              void* d_out, int out_size, void* d_ws, size_t ws_size,
                              hipStream_t stream) {
    const float* inp   = (const float*)d_in[0];  // (M,B,L,S)
    const float* tauk  = (const float*)d_in[1];  // (M,NR)
    const float* exch  = (const float*)d_in[2];  // (M,K,S,S)
    const float* equil = (const float*)d_in[3];  // (M,K,S)
    const float* pmrk  = (const float*)d_in[4];  // (M,K)
    const int*   ridx  = (const int*)d_in[5];    // (M,B)
    float* outp = (float*)d_out;

    float* Qpow = (float*)d_ws;                          // 89.6 KB
    float* Pws  = Qpow + (size_t)M_ * K_ * NTERM * 400;  // 1.28 MB

    qpow_kernel<<<M_ * K_, 512, 0, stream>>>(exch, equil, Qpow);
    pbuild_kernel<<<M_ * NR_ * K_, 512, 0, stream>>>(Qpow, tauk, pmrk, Pws);
    einsum_kernel<<<M_ * B_ * 4, TPB3, 0, stream>>>(inp, Pws, ridx, outp);
}